// Round 9
// baseline (293.456 us; speedup 1.0000x reference)
//
#include <hip/hip_runtime.h>

// Fused 3-branch shared LSTM(H1=3) -> LSTM(H2=9) -> dense(3)+sigmoid, T=2048, B=1024.
// 9 lanes per chain (lane u: LSTM1 unit (u/3,u%3), LSTM2 unit u), 7 chains/wave.
// Weights in VGPRs pre-scaled by -log2(e); merged-rcp sigmoid cells; scaled cell state.
// Rotated gather order (slot k = unit (3p+k)%9) so slots 0..2 are own-branch h.
// R9: SOFTWARE-PIPELINED STAGES. Iteration i computes LSTM1(i) from y4g(i-1),
// LSTM2(i-1) from y4g(i-1)+h2g(i-2), dense(i-2) from h2g(i-2) -- all inputs were
// gathered a FULL iteration earlier, so no ds_bpermute latency sits on the
// critical path. Gathers for h1v(i), h2v(i-1) issue at iteration end with ~450cy
// slack. 1 wave/SIMD (waves_per_eu(1,1), 64-thr blocks), KC=6 -> 882 waves, 1 round.

#define BATCH  1024
#define SEQT   2048
#define KC     6
#define WPC    147    // ceil(1024/7) waves per chunk slot
#define WARMUP 64

typedef float f32x2 __attribute__((ext_vector_type(2)));

__device__ __forceinline__ float fexp2(float v) { return __builtin_amdgcn_exp2f(v); }
__device__ __forceinline__ float frcp(float v)  { return __builtin_amdgcn_rcpf(v); }
__device__ __forceinline__ float bperm(int addr, float v) {
    return __int_as_float(__builtin_amdgcn_ds_bpermute(addr, __float_as_int(v)));
}

__global__ __launch_bounds__(64) __attribute__((amdgpu_waves_per_eu(1, 1)))
void fused_lstm3(const float* __restrict__ x,
                 const float* __restrict__ wk1, const float* __restrict__ wr1,
                 const float* __restrict__ b1,
                 const float* __restrict__ wk2, const float* __restrict__ wr2,
                 const float* __restrict__ b2,
                 const float* __restrict__ wdn, const float* __restrict__ bdn,
                 float* __restrict__ out)
{
    const int lane  = threadIdx.x;               // 64-thread block = one wave
    const int group = lane / 9;                  // 7 groups of 9 lanes; lane 63 idle
    const bool act  = (group < 7);
    const int u     = act ? (lane - group * 9) : 0;

    const int wv = blockIdx.x;                   // one wave per block
    int s        = wv / WPC;
    const int bw = wv - s * WPC;
    const bool vs = (s < KC);
    if (!vs) s = KC - 1;
    int b = bw * 7 + (act ? group : 6);
    const bool vb = (b < BATCH);
    if (!vb) b = BATCH - 1;
    const bool do_store = vs && vb && act && (u < 3);

    const int t_start = (SEQT * s) / KC;
    const int t_end   = (SEQT * (s + 1)) / KC;
    const int t0      = (t_start > WARMUP) ? (t_start - WARMUP) : 0;

    const int p  = u / 3;                        // branch index
    const int q  = u - p * 3;                    // unit within branch

    const float SS = -1.44269504088896f;         // -log2(e) folded into gate weights

    // rotated gather addresses: slot k <- unit (3p+k)%9 of this group
    int offv[9];
#pragma unroll
    for (int k = 0; k < 9; ++k) {
        int j = 3 * p + k; j = (j >= 9) ? j - 9 : j;
        offv[k] = (group * 9 + j) << 2;
    }

    // ---- per-lane weights, pre-scaled, packed in gate-pairs (i,f) and (g,o) ----
    f32x2 w1a[2], w1b[2], w1h[2][3], b1p[2];
    f32x2 w2xp[2][9], w2hp[2][9], b2p[2];
    float wdk[9], dbu;
#pragma unroll
    for (int pr = 0; pr < 2; ++pr) {
        const int g0 = 2 * pr, g1 = 2 * pr + 1;
        const int c0 = g0 * 3 + q, c1 = g1 * 3 + q;      // LSTM1 cols (gate-major i,f,g,o)
        w1a[pr].x = wk1[c0] * SS;       w1a[pr].y = wk1[c1] * SS;
        w1b[pr].x = wk1[12 + c0] * SS;  w1b[pr].y = wk1[12 + c1] * SS;
#pragma unroll
        for (int k = 0; k < 3; ++k) {
            w1h[pr][k].x = wr1[k * 12 + c0] * SS;
            w1h[pr][k].y = wr1[k * 12 + c1] * SS;
        }
        b1p[pr].x = b1[c0] * SS;  b1p[pr].y = b1[c1] * SS;
        const int d0 = g0 * 9 + u, d1 = g1 * 9 + u;      // LSTM2 cols
#pragma unroll
        for (int k = 0; k < 9; ++k) {
            const int jj = (offv[k] >> 2) - group * 9;   // permuted unit index
            w2xp[pr][k].x = wk2[jj * 36 + d0] * SS;
            w2xp[pr][k].y = wk2[jj * 36 + d1] * SS;
            w2hp[pr][k].x = wr2[jj * 36 + d0] * SS;
            w2hp[pr][k].y = wr2[jj * 36 + d1] * SS;
        }
        b2p[pr].x = b2[d0] * SS;  b2p[pr].y = b2[d1] * SS;
    }
    {
        const int d = (u < 3) ? u : 0;
#pragma unroll
        for (int k = 0; k < 9; ++k) {
            const int jj = (offv[k] >> 2) - group * 9;
            wdk[k] = wdn[jj * 3 + d] * SS;
        }
        dbu = bdn[d] * SS;
    }

    // ---- state ----
    // y4g = gathered y4 of step (i-1); h2g = gathered h2 of step (i-2)
    float cm1 = 0.f, cm2 = 0.f;                  // scaled cell states (-log2e * c)
    float y4g[9], h2g[9];
#pragma unroll
    for (int k = 0; k < 9; ++k) { y4g[k] = 0.f; h2g[k] = 0.f; }

    // 32-bit element offsets from SGPR bases
    int xo = (b * SEQT + t0) * 6 + 2 * p;
    int oo = (b * SEQT + t_start) * 3 + u;

    // ---- prologue: LSTM1 step t0 (y4(t0-1) = 0), issue its gather ----
    {
        const float2 xv = *(const float2*)(x + xo);
        f32x2 zA = b1p[0], zB = b1p[1];
        zA += w1a[0] * xv.x;  zB += w1a[1] * xv.x;
        zA += w1b[0] * xv.y;  zB += w1b[1] * xv.y;
        const float eI = fexp2(zA.x), eF = fexp2(zA.y);
        const float eG = fexp2(zB.x), eO = fexp2(zB.y);
        const float f   = frcp(1.0f + eF);
        const float pig = (1.0f + eI) * (1.0f + eG);
        cm1 = f * cm1 + frcp(-0.69314718056f * pig);
        const float ec = fexp2(cm1);
        const float h1v = frcp((1.0f + eO) * (1.0f + ec));
#pragma unroll
        for (int k = 0; k < 9; ++k) y4g[k] = bperm(offv[k], h1v);
    }

    // x ring: entering iteration i, xv0 = x(i), xv1 = x(i+1), xo -> row min(i+2, t_end-1)
    float2 xv0 = *(const float2*)(x + xo + 6);
    float2 xv1 = *(const float2*)(x + xo + 12);
    xo += 18;

#pragma unroll 2
    for (int i = t0 + 1; i <= t_end; ++i) {
        // prefetch x(i+2) (offset frozen at row t_end-1)
        const float2 xn = *(const float2*)(x + xo);
        xo += (i < t_end - 3) ? 6 : 0;

        // ---- LSTM1 step i (reads y4g slots 0..2 = own-branch h1(i-1)) ----
        f32x2 zA = b1p[0], zB = b1p[1];
        zA += w1a[0] * xv0.x;     zB += w1a[1] * xv0.x;
        zA += w1b[0] * xv0.y;     zB += w1b[1] * xv0.y;
        zA += w1h[0][0] * y4g[0]; zB += w1h[1][0] * y4g[0];
        zA += w1h[0][1] * y4g[1]; zB += w1h[1][1] * y4g[1];
        zA += w1h[0][2] * y4g[2]; zB += w1h[1][2] * y4g[2];

        // ---- LSTM2 step i-1: full z from ready y4g + h2g (no DS wait) ----
        f32x2 z2A = b2p[0], z2B = b2p[1];
        f32x2 z2A1 = (f32x2)(0.f), z2B1 = (f32x2)(0.f);
#pragma unroll
        for (int k = 0; k < 4; ++k) { z2A  += w2hp[0][k] * h2g[k]; z2B  += w2hp[1][k] * h2g[k]; }
#pragma unroll
        for (int k = 4; k < 9; ++k) { z2A1 += w2hp[0][k] * h2g[k]; z2B1 += w2hp[1][k] * h2g[k]; }
#pragma unroll
        for (int k = 0; k < 4; ++k) { z2A  += w2xp[0][k] * y4g[k]; z2B  += w2xp[1][k] * y4g[k]; }
#pragma unroll
        for (int k = 4; k < 9; ++k) { z2A1 += w2xp[0][k] * y4g[k]; z2B1 += w2xp[1][k] * y4g[k]; }
        z2A += z2A1; z2B += z2B1;

        // ---- dense step i-2 (reads h2g = h2(i-2)) ----
        if (i >= t_start + 2) {
            float a0 = dbu, a1 = 0.f;
#pragma unroll
            for (int k = 0; k < 4; ++k) a0 += h2g[k] * wdk[k];
#pragma unroll
            for (int k = 4; k < 9; ++k) a1 += h2g[k] * wdk[k];
            const float yv = frcp(1.0f + fexp2(a0 + a1));
            if (do_store) out[oo] = yv;
            oo += 3;
        }

        // ---- finish LSTM1 cell -> h1v(i); issue y4 gather ----
        {
            const float eI = fexp2(zA.x), eF = fexp2(zA.y);
            const float eG = fexp2(zB.x), eO = fexp2(zB.y);
            const float f   = frcp(1.0f + eF);
            const float pig = (1.0f + eI) * (1.0f + eG);
            cm1 = f * cm1 + frcp(-0.69314718056f * pig);
            const float ec = fexp2(cm1);
            const float h1v = frcp((1.0f + eO) * (1.0f + ec));
#pragma unroll
            for (int k = 0; k < 9; ++k) y4g[k] = bperm(offv[k], h1v);
        }

        // ---- finish LSTM2 cell -> h2v(i-1); issue h2 gather ----
        {
            const float eI = fexp2(z2A.x), eF = fexp2(z2A.y);
            const float eG = fexp2(z2B.x), eO = fexp2(z2B.y);
            const float f   = frcp(1.0f + eF);
            const float pig = (1.0f + eI) * (1.0f + eG);
            cm2 = f * cm2 + frcp(-0.69314718056f * pig);
            const float ec = fexp2(cm2);
            const float h2v = frcp((1.0f + eO) * (1.0f + ec));
#pragma unroll
            for (int k = 0; k < 9; ++k) h2g[k] = bperm(offv[k], h2v);
        }

        xv0 = xv1; xv1 = xn;
    }

    // ---- epilogue: dense for step t_end-1 (h2g gathered at i = t_end) ----
    {
        float a0 = dbu, a1 = 0.f;
#pragma unroll
        for (int k = 0; k < 4; ++k) a0 += h2g[k] * wdk[k];
#pragma unroll
        for (int k = 4; k < 9; ++k) a1 += h2g[k] * wdk[k];
        const float yv = frcp(1.0f + fexp2(a0 + a1));
        if (do_store) out[oo] = yv;
    }
}

extern "C" void kernel_launch(void* const* d_in, const int* in_sizes, int n_in,
                              void* d_out, int out_size, void* d_ws, size_t ws_size,
                              hipStream_t stream) {
    (void)in_sizes; (void)n_in; (void)d_ws; (void)ws_size; (void)out_size;
    // 882 one-wave blocks (64 thr): <= 1024 SIMDs -> single round, no stragglers
    hipLaunchKernelGGL(fused_lstm3, dim3(KC * WPC), dim3(64), 0, stream,
                       (const float*)d_in[0],
                       (const float*)d_in[1], (const float*)d_in[2], (const float*)d_in[3],
                       (const float*)d_in[4], (const float*)d_in[5], (const float*)d_in[6],
                       (const float*)d_in[7], (const float*)d_in[8],
                       (float*)d_out);
}

// Round 10
// 228.626 us; speedup vs baseline: 1.2836x; 1.2836x over previous
//
#include <hip/hip_runtime.h>

// Fused 3-branch shared LSTM(H1=3) -> LSTM(H2=9) -> dense(3)+sigmoid, T=2048, B=1024.
// 9 lanes per chain (lane u: LSTM1 unit (u/3,u%3), LSTM2 unit u), 7 chains/wave.
// Weights in VGPRs pre-scaled by -log2(e); merged-rcp sigmoid cells; scaled cell state.
// Rotated gather order (slot k = unit (3p+k)%9) so slots 0..2 are own-branch h.
// R10: R8's lean body (132 VGPR demand) at THREE clean waves/SIMD:
// waves_per_eu(3,3) budget ~170 >= 132 -> no AGPR shuttle (R6's body was ~165 and
// split 84/84; R8 proved the lean body's true demand). KC=20 -> 2940 waves ~ 2.87
// resident/SIMD, single round. Co-resident waves fill the ~1200cy/step chain latency
// that R8/R9 proved cannot be hidden within one wave.

#define BATCH  1024
#define SEQT   2048
#define KC     20
#define WPC    147    // ceil(1024/7) waves per chunk slot
#define WARMUP 64

typedef float f32x2 __attribute__((ext_vector_type(2)));

__device__ __forceinline__ float fexp2(float v) { return __builtin_amdgcn_exp2f(v); }
__device__ __forceinline__ float frcp(float v)  { return __builtin_amdgcn_rcpf(v); }
__device__ __forceinline__ float bperm(int addr, float v) {
    return __int_as_float(__builtin_amdgcn_ds_bpermute(addr, __float_as_int(v)));
}

__global__ __launch_bounds__(64) __attribute__((amdgpu_waves_per_eu(3, 3)))
void fused_lstm3(const float* __restrict__ x,
                 const float* __restrict__ wk1, const float* __restrict__ wr1,
                 const float* __restrict__ b1,
                 const float* __restrict__ wk2, const float* __restrict__ wr2,
                 const float* __restrict__ b2,
                 const float* __restrict__ wdn, const float* __restrict__ bdn,
                 float* __restrict__ out)
{
    const int lane  = threadIdx.x;               // 64-thread block = one wave
    const int group = lane / 9;                  // 7 groups of 9 lanes; lane 63 idle
    const bool act  = (group < 7);
    const int u     = act ? (lane - group * 9) : 0;

    const int wv = blockIdx.x;                   // one wave per block
    int s        = wv / WPC;
    const int bw = wv - s * WPC;
    const bool vs = (s < KC);
    if (!vs) s = KC - 1;
    int b = bw * 7 + (act ? group : 6);
    const bool vb = (b < BATCH);
    if (!vb) b = BATCH - 1;
    const bool do_store = vs && vb && act && (u < 3);

    const int t_start = (SEQT * s) / KC;
    const int t_end   = (SEQT * (s + 1)) / KC;
    const int t0      = (t_start > WARMUP) ? (t_start - WARMUP) : 0;

    const int p  = u / 3;                        // branch index
    const int q  = u - p * 3;                    // unit within branch

    const float SS = -1.44269504088896f;         // -log2(e) folded into gate weights

    // rotated gather addresses: slot k <- unit (3p+k)%9 of this group
    int offv[9];
#pragma unroll
    for (int k = 0; k < 9; ++k) {
        int j = 3 * p + k; j = (j >= 9) ? j - 9 : j;
        offv[k] = (group * 9 + j) << 2;
    }

    // ---- per-lane weights, pre-scaled, packed in gate-pairs (i,f) and (g,o) ----
    f32x2 w1a[2], w1b[2], w1h[2][3], b1p[2];
    f32x2 w2xp[2][9], w2hp[2][9], b2p[2];
    float wdk[9], dbu;
#pragma unroll
    for (int pr = 0; pr < 2; ++pr) {
        const int g0 = 2 * pr, g1 = 2 * pr + 1;
        const int c0 = g0 * 3 + q, c1 = g1 * 3 + q;      // LSTM1 cols (gate-major i,f,g,o)
        w1a[pr].x = wk1[c0] * SS;       w1a[pr].y = wk1[c1] * SS;
        w1b[pr].x = wk1[12 + c0] * SS;  w1b[pr].y = wk1[12 + c1] * SS;
#pragma unroll
        for (int k = 0; k < 3; ++k) {
            w1h[pr][k].x = wr1[k * 12 + c0] * SS;
            w1h[pr][k].y = wr1[k * 12 + c1] * SS;
        }
        b1p[pr].x = b1[c0] * SS;  b1p[pr].y = b1[c1] * SS;
        const int d0 = g0 * 9 + u, d1 = g1 * 9 + u;      // LSTM2 cols
#pragma unroll
        for (int k = 0; k < 9; ++k) {
            const int jj = (offv[k] >> 2) - group * 9;   // permuted unit index
            w2xp[pr][k].x = wk2[jj * 36 + d0] * SS;
            w2xp[pr][k].y = wk2[jj * 36 + d1] * SS;
            w2hp[pr][k].x = wr2[jj * 36 + d0] * SS;
            w2hp[pr][k].y = wr2[jj * 36 + d1] * SS;
        }
        b2p[pr].x = b2[d0] * SS;  b2p[pr].y = b2[d1] * SS;
    }
    {
        const int d = (u < 3) ? u : 0;
#pragma unroll
        for (int k = 0; k < 9; ++k) {
            const int jj = (offv[k] >> 2) - group * 9;
            wdk[k] = wdn[jj * 3 + d] * SS;
        }
        dbu = bdn[d] * SS;
    }

    // ---- state ----
    float cm1 = 0.f, cm2 = 0.f;                  // scaled cell states (-log2e * c)
    float y4g[9], h2g[9];
#pragma unroll
    for (int k = 0; k < 9; ++k) { y4g[k] = 0.f; h2g[k] = 0.f; }

    // 32-bit element offsets from SGPR bases (x = 48 MB, out = 25 MB: both < 4 GB)
    int xo = (b * SEQT + t0) * 6 + 2 * p;
    int oo = (b * SEQT + t_start) * 3 + u;

    // depth-2 prefetch ring (chunk length >= 102, so +12 is safe)
    float2 xv0 = *(const float2*)(x + xo);
    float2 xv1 = *(const float2*)(x + xo + 6);
    xo += 12;

#pragma unroll 2
    for (int t = t0; t < t_end; ++t) {
        // prefetch x for t+2 (offset freezes near chunk end)
        const float2 xn = *(const float2*)(x + xo);
        xo += ((t + 3) < t_end) ? 6 : 0;

        // ---- LSTM-1 (slots 0..2 are this lane's branch h); pk_fma pairs ----
        f32x2 zA = b1p[0], zB = b1p[1];
        zA += w1a[0] * xv0.x;    zB += w1a[1] * xv0.x;
        zA += w1b[0] * xv0.y;    zB += w1b[1] * xv0.y;
        zA += w1h[0][0] * y4g[0]; zB += w1h[1][0] * y4g[0];
        zA += w1h[0][1] * y4g[1]; zB += w1h[1][1] * y4g[1];
        zA += w1h[0][2] * y4g[2]; zB += w1h[1][2] * y4g[2];
        {
            const float eI = fexp2(zA.x), eF = fexp2(zA.y);
            const float eG = fexp2(zB.x), eO = fexp2(zB.y);
            const float f   = frcp(1.0f + eF);
            const float pig = (1.0f + eI) * (1.0f + eG);
            cm1 = f * cm1 + frcp(-0.69314718056f * pig);
            const float ec = fexp2(cm1);
            const float h1v = frcp((1.0f + eO) * (1.0f + ec));

            // ---- issue y4 gathers immediately (rotated order) ----
#pragma unroll
            for (int k = 0; k < 9; ++k) y4g[k] = bperm(offv[k], h1v);
        }

        // ---- dense + store for step t-1 (old h2g; fills DS window) ----
        if (t > t_start) {
            float a0 = dbu, a1 = 0.f;
#pragma unroll
            for (int k = 0; k < 4; ++k) a0 += h2g[k] * wdk[k];
#pragma unroll
            for (int k = 4; k < 9; ++k) a1 += h2g[k] * wdk[k];
            const float yv = frcp(1.0f + fexp2(a0 + a1));
            if (do_store) out[oo] = yv;
            oo += 3;
        }

        // ---- zh: LSTM2 h-recurrence partials (old h2g; fills DS window) ----
        f32x2 zhA = b2p[0], zhB = b2p[1];
        f32x2 zhA1 = (f32x2)(0.f), zhB1 = (f32x2)(0.f);
#pragma unroll
        for (int k = 0; k < 4; ++k) { zhA  += w2hp[0][k] * h2g[k]; zhB  += w2hp[1][k] * h2g[k]; }
#pragma unroll
        for (int k = 4; k < 9; ++k) { zhA1 += w2hp[0][k] * h2g[k]; zhB1 += w2hp[1][k] * h2g[k]; }
        zhA += zhA1; zhB += zhB1;

        // ---- finish LSTM2 (waits on y4 gathers here) ----
        f32x2 z2A = zhA, z2B = zhB;
        f32x2 z2A1 = (f32x2)(0.f), z2B1 = (f32x2)(0.f);
#pragma unroll
        for (int k = 0; k < 4; ++k) { z2A  += w2xp[0][k] * y4g[k]; z2B  += w2xp[1][k] * y4g[k]; }
#pragma unroll
        for (int k = 4; k < 9; ++k) { z2A1 += w2xp[0][k] * y4g[k]; z2B1 += w2xp[1][k] * y4g[k]; }
        z2A += z2A1; z2B += z2B1;
        {
            const float eI = fexp2(z2A.x), eF = fexp2(z2A.y);
            const float eG = fexp2(z2B.x), eO = fexp2(z2B.y);
            const float f   = frcp(1.0f + eF);
            const float pig = (1.0f + eI) * (1.0f + eG);
            cm2 = f * cm2 + frcp(-0.69314718056f * pig);
            const float ec = fexp2(cm2);
            const float h2v = frcp((1.0f + eO) * (1.0f + ec));

            // ---- issue h2 gathers immediately ----
#pragma unroll
            for (int k = 0; k < 9; ++k) h2g[k] = bperm(offv[k], h2v);
        }

        xv0 = xv1; xv1 = xn;
    }

    // ---- epilogue: dense + store for the final step (t_end-1) ----
    {
        float a0 = dbu, a1 = 0.f;
#pragma unroll
        for (int k = 0; k < 4; ++k) a0 += h2g[k] * wdk[k];
#pragma unroll
        for (int k = 4; k < 9; ++k) a1 += h2g[k] * wdk[k];
        const float yv = frcp(1.0f + fexp2(a0 + a1));
        if (do_store) out[oo] = yv;
    }
}

extern "C" void kernel_launch(void* const* d_in, const int* in_sizes, int n_in,
                              void* d_out, int out_size, void* d_ws, size_t ws_size,
                              hipStream_t stream) {
    (void)in_sizes; (void)n_in; (void)d_ws; (void)ws_size; (void)out_size;
    // 2940 one-wave blocks: ~2.87 waves/SIMD resident (cap 3), single round
    hipLaunchKernelGGL(fused_lstm3, dim3(KC * WPC), dim3(64), 0, stream,
                       (const float*)d_in[0],
                       (const float*)d_in[1], (const float*)d_in[2], (const float*)d_in[3],
                       (const float*)d_in[4], (const float*)d_in[5], (const float*)d_in[6],
                       (const float*)d_in[7], (const float*)d_in[8],
                       (float*)d_out);
}

// Round 11
// 226.736 us; speedup vs baseline: 1.2943x; 1.0083x over previous
//
#include <hip/hip_runtime.h>

// Fused 3-branch shared LSTM(H1=3) -> LSTM(H2=9) -> dense(3)+sigmoid, T=2048, B=1024.
// 9 lanes per chain (lane u: LSTM1 unit (u/3,u%3), LSTM2 unit u), 7 chains/wave.
// Weights in VGPRs pre-scaled by -log2(e); merged-rcp sigmoid cells; scaled cell state.
// Rotated gather order (slot k = unit (3p+k)%9) so slots 0..2 are own-branch h.
// R11: R10 + amdgpu_agpr_alloc(0). R4-R10 evidence: at any waves_per_eu budget <256
// the backend reserves HALF the unified VGPR file for AGPRs (arch = budget/2) even
// with no MFMA, shuttling the overflow via v_accvgpr_read (~30-40% of issue).
// agpr_alloc(0) disables the reservation: arch budget 168 >= demand 132 -> 3 clean
// waves/SIMD. KC=20 -> 2940 waves = 96% of 3-wave capacity, single round.

#define BATCH  1024
#define SEQT   2048
#define KC     20
#define WPC    147    // ceil(1024/7) waves per chunk slot
#define WARMUP 64

typedef float f32x2 __attribute__((ext_vector_type(2)));

__device__ __forceinline__ float fexp2(float v) { return __builtin_amdgcn_exp2f(v); }
__device__ __forceinline__ float frcp(float v)  { return __builtin_amdgcn_rcpf(v); }
__device__ __forceinline__ float bperm(int addr, float v) {
    return __int_as_float(__builtin_amdgcn_ds_bpermute(addr, __float_as_int(v)));
}

#if __has_attribute(amdgpu_agpr_alloc)
#define NO_AGPR __attribute__((amdgpu_agpr_alloc(0)))
#else
#define NO_AGPR
#endif

__global__ __launch_bounds__(64) __attribute__((amdgpu_waves_per_eu(3, 3))) NO_AGPR
void fused_lstm3(const float* __restrict__ x,
                 const float* __restrict__ wk1, const float* __restrict__ wr1,
                 const float* __restrict__ b1,
                 const float* __restrict__ wk2, const float* __restrict__ wr2,
                 const float* __restrict__ b2,
                 const float* __restrict__ wdn, const float* __restrict__ bdn,
                 float* __restrict__ out)
{
    const int lane  = threadIdx.x;               // 64-thread block = one wave
    const int group = lane / 9;                  // 7 groups of 9 lanes; lane 63 idle
    const bool act  = (group < 7);
    const int u     = act ? (lane - group * 9) : 0;

    const int wv = blockIdx.x;                   // one wave per block
    int s        = wv / WPC;
    const int bw = wv - s * WPC;
    const bool vs = (s < KC);
    if (!vs) s = KC - 1;
    int b = bw * 7 + (act ? group : 6);
    const bool vb = (b < BATCH);
    if (!vb) b = BATCH - 1;
    const bool do_store = vs && vb && act && (u < 3);

    const int t_start = (SEQT * s) / KC;
    const int t_end   = (SEQT * (s + 1)) / KC;
    const int t0      = (t_start > WARMUP) ? (t_start - WARMUP) : 0;

    const int p  = u / 3;                        // branch index
    const int q  = u - p * 3;                    // unit within branch

    const float SS = -1.44269504088896f;         // -log2(e) folded into gate weights

    // rotated gather addresses: slot k <- unit (3p+k)%9 of this group
    int offv[9];
#pragma unroll
    for (int k = 0; k < 9; ++k) {
        int j = 3 * p + k; j = (j >= 9) ? j - 9 : j;
        offv[k] = (group * 9 + j) << 2;
    }

    // ---- per-lane weights, pre-scaled, packed in gate-pairs (i,f) and (g,o) ----
    f32x2 w1a[2], w1b[2], w1h[2][3], b1p[2];
    f32x2 w2xp[2][9], w2hp[2][9], b2p[2];
    float wdk[9], dbu;
#pragma unroll
    for (int pr = 0; pr < 2; ++pr) {
        const int g0 = 2 * pr, g1 = 2 * pr + 1;
        const int c0 = g0 * 3 + q, c1 = g1 * 3 + q;      // LSTM1 cols (gate-major i,f,g,o)
        w1a[pr].x = wk1[c0] * SS;       w1a[pr].y = wk1[c1] * SS;
        w1b[pr].x = wk1[12 + c0] * SS;  w1b[pr].y = wk1[12 + c1] * SS;
#pragma unroll
        for (int k = 0; k < 3; ++k) {
            w1h[pr][k].x = wr1[k * 12 + c0] * SS;
            w1h[pr][k].y = wr1[k * 12 + c1] * SS;
        }
        b1p[pr].x = b1[c0] * SS;  b1p[pr].y = b1[c1] * SS;
        const int d0 = g0 * 9 + u, d1 = g1 * 9 + u;      // LSTM2 cols
#pragma unroll
        for (int k = 0; k < 9; ++k) {
            const int jj = (offv[k] >> 2) - group * 9;   // permuted unit index
            w2xp[pr][k].x = wk2[jj * 36 + d0] * SS;
            w2xp[pr][k].y = wk2[jj * 36 + d1] * SS;
            w2hp[pr][k].x = wr2[jj * 36 + d0] * SS;
            w2hp[pr][k].y = wr2[jj * 36 + d1] * SS;
        }
        b2p[pr].x = b2[d0] * SS;  b2p[pr].y = b2[d1] * SS;
    }
    {
        const int d = (u < 3) ? u : 0;
#pragma unroll
        for (int k = 0; k < 9; ++k) {
            const int jj = (offv[k] >> 2) - group * 9;
            wdk[k] = wdn[jj * 3 + d] * SS;
        }
        dbu = bdn[d] * SS;
    }

    // ---- state ----
    float cm1 = 0.f, cm2 = 0.f;                  // scaled cell states (-log2e * c)
    float y4g[9], h2g[9];
#pragma unroll
    for (int k = 0; k < 9; ++k) { y4g[k] = 0.f; h2g[k] = 0.f; }

    // 32-bit element offsets from SGPR bases (x = 48 MB, out = 25 MB: both < 4 GB)
    int xo = (b * SEQT + t0) * 6 + 2 * p;
    int oo = (b * SEQT + t_start) * 3 + u;

    // depth-2 prefetch ring (chunk length >= 102, so +12 is safe)
    float2 xv0 = *(const float2*)(x + xo);
    float2 xv1 = *(const float2*)(x + xo + 6);
    xo += 12;

#pragma unroll 2
    for (int t = t0; t < t_end; ++t) {
        // prefetch x for t+2 (offset freezes near chunk end)
        const float2 xn = *(const float2*)(x + xo);
        xo += ((t + 3) < t_end) ? 6 : 0;

        // ---- LSTM-1 (slots 0..2 are this lane's branch h); pk_fma pairs ----
        f32x2 zA = b1p[0], zB = b1p[1];
        zA += w1a[0] * xv0.x;    zB += w1a[1] * xv0.x;
        zA += w1b[0] * xv0.y;    zB += w1b[1] * xv0.y;
        zA += w1h[0][0] * y4g[0]; zB += w1h[1][0] * y4g[0];
        zA += w1h[0][1] * y4g[1]; zB += w1h[1][1] * y4g[1];
        zA += w1h[0][2] * y4g[2]; zB += w1h[1][2] * y4g[2];
        {
            const float eI = fexp2(zA.x), eF = fexp2(zA.y);
            const float eG = fexp2(zB.x), eO = fexp2(zB.y);
            const float f   = frcp(1.0f + eF);
            const float pig = (1.0f + eI) * (1.0f + eG);
            cm1 = f * cm1 + frcp(-0.69314718056f * pig);
            const float ec = fexp2(cm1);
            const float h1v = frcp((1.0f + eO) * (1.0f + ec));

            // ---- issue y4 gathers immediately (rotated order) ----
#pragma unroll
            for (int k = 0; k < 9; ++k) y4g[k] = bperm(offv[k], h1v);
        }

        // ---- dense + store for step t-1 (old h2g; fills DS window) ----
        if (t > t_start) {
            float a0 = dbu, a1 = 0.f;
#pragma unroll
            for (int k = 0; k < 4; ++k) a0 += h2g[k] * wdk[k];
#pragma unroll
            for (int k = 4; k < 9; ++k) a1 += h2g[k] * wdk[k];
            const float yv = frcp(1.0f + fexp2(a0 + a1));
            if (do_store) out[oo] = yv;
            oo += 3;
        }

        // ---- zh: LSTM2 h-recurrence partials (old h2g; fills DS window) ----
        f32x2 zhA = b2p[0], zhB = b2p[1];
        f32x2 zhA1 = (f32x2)(0.f), zhB1 = (f32x2)(0.f);
#pragma unroll
        for (int k = 0; k < 4; ++k) { zhA  += w2hp[0][k] * h2g[k]; zhB  += w2hp[1][k] * h2g[k]; }
#pragma unroll
        for (int k = 4; k < 9; ++k) { zhA1 += w2hp[0][k] * h2g[k]; zhB1 += w2hp[1][k] * h2g[k]; }
        zhA += zhA1; zhB += zhB1;

        // ---- finish LSTM2 (waits on y4 gathers here) ----
        f32x2 z2A = zhA, z2B = zhB;
        f32x2 z2A1 = (f32x2)(0.f), z2B1 = (f32x2)(0.f);
#pragma unroll
        for (int k = 0; k < 4; ++k) { z2A  += w2xp[0][k] * y4g[k]; z2B  += w2xp[1][k] * y4g[k]; }
#pragma unroll
        for (int k = 4; k < 9; ++k) { z2A1 += w2xp[0][k] * y4g[k]; z2B1 += w2xp[1][k] * y4g[k]; }
        z2A += z2A1; z2B += z2B1;
        {
            const float eI = fexp2(z2A.x), eF = fexp2(z2A.y);
            const float eG = fexp2(z2B.x), eO = fexp2(z2B.y);
            const float f   = frcp(1.0f + eF);
            const float pig = (1.0f + eI) * (1.0f + eG);
            cm2 = f * cm2 + frcp(-0.69314718056f * pig);
            const float ec = fexp2(cm2);
            const float h2v = frcp((1.0f + eO) * (1.0f + ec));

            // ---- issue h2 gathers immediately ----
#pragma unroll
            for (int k = 0; k < 9; ++k) h2g[k] = bperm(offv[k], h2v);
        }

        xv0 = xv1; xv1 = xn;
    }

    // ---- epilogue: dense + store for the final step (t_end-1) ----
    {
        float a0 = dbu, a1 = 0.f;
#pragma unroll
        for (int k = 0; k < 4; ++k) a0 += h2g[k] * wdk[k];
#pragma unroll
        for (int k = 4; k < 9; ++k) a1 += h2g[k] * wdk[k];
        const float yv = frcp(1.0f + fexp2(a0 + a1));
        if (do_store) out[oo] = yv;
    }
}

extern "C" void kernel_launch(void* const* d_in, const int* in_sizes, int n_in,
                              void* d_out, int out_size, void* d_ws, size_t ws_size,
                              hipStream_t stream) {
    (void)in_sizes; (void)n_in; (void)d_ws; (void)ws_size; (void)out_size;
    // 2940 one-wave blocks: ~2.87 waves/SIMD resident (cap 3), single round
    hipLaunchKernelGGL(fused_lstm3, dim3(KC * WPC), dim3(64), 0, stream,
                       (const float*)d_in[0],
                       (const float*)d_in[1], (const float*)d_in[2], (const float*)d_in[3],
                       (const float*)d_in[4], (const float*)d_in[5], (const float*)d_in[6],
                       (const float*)d_in[7], (const float*)d_in[8],
                       (float*)d_out);
}